// Round 5
// baseline (101.600 us; speedup 1.0000x reference)
//
#include <hip/hip_runtime.h>

// Reference returns (x, y) unchanged — _block_scores is computed and discarded.
// d_out = concat(flat(x), flat(y)) in float32. Pure D2D copy, memory-bound.
// 268 MB read + 268 MB write; working set (537 MB) > L3 (256 MB) -> stream
// with nontemporal load/store (nt flag). Unroll x2 per range: 4 independent
// 16B nt loads in flight before the first dependent store wait (MLP).

typedef float f4 __attribute__((ext_vector_type(4)));

__global__ __launch_bounds__(256)
void copy_xy_kernel(const f4* __restrict__ x, const f4* __restrict__ y,
                    f4* __restrict__ ox, f4* __restrict__ oy,
                    size_t n4) {
    const size_t stride = (size_t)gridDim.x * blockDim.x;
    size_t i = (size_t)blockIdx.x * blockDim.x + threadIdx.x;

    // Main unrolled loop: 4 independent loads, then 4 stores.
    for (; i + stride < n4; i += 2 * stride) {
        const size_t j = i + stride;
        f4 a0 = __builtin_nontemporal_load(&x[i]);
        f4 a1 = __builtin_nontemporal_load(&x[j]);
        f4 b0 = __builtin_nontemporal_load(&y[i]);
        f4 b1 = __builtin_nontemporal_load(&y[j]);
        __builtin_nontemporal_store(a0, &ox[i]);
        __builtin_nontemporal_store(a1, &ox[j]);
        __builtin_nontemporal_store(b0, &oy[i]);
        __builtin_nontemporal_store(b1, &oy[j]);
    }
    // Tail (not taken for this problem's exact sizes, kept for safety).
    for (; i < n4; i += stride) {
        f4 a = __builtin_nontemporal_load(&x[i]);
        f4 b = __builtin_nontemporal_load(&y[i]);
        __builtin_nontemporal_store(a, &ox[i]);
        __builtin_nontemporal_store(b, &oy[i]);
    }
}

extern "C" void kernel_launch(void* const* d_in, const int* in_sizes, int n_in,
                              void* d_out, int out_size, void* d_ws, size_t ws_size,
                              hipStream_t stream) {
    const size_t nx = (size_t)in_sizes[0];  // x: 128*64*64*64 f32
    const size_t ny = (size_t)in_sizes[1];  // y: 128*64*64*64 f32 (== nx)
    const size_t n4 = nx / 4;               // per-range float4 count

    const f4* x = (const f4*)d_in[0];
    const f4* y = (const f4*)d_in[1];
    f4* ox = (f4*)d_out;
    f4* oy = (f4*)((char*)d_out + nx * sizeof(float));

    copy_xy_kernel<<<2048, 256, 0, stream>>>(x, y, ox, oy, n4);
}

// Round 6
// 93.885 us; speedup vs baseline: 1.0822x; 1.0822x over previous
//
#include <hip/hip_runtime.h>

// Reference returns (x, y) unchanged — _block_scores is computed and discarded.
// d_out = concat(flat(x), flat(y)) in float32. Pure D2D copy, memory-bound.
// 268 MB read + 268 MB write; working set (537 MB) > L3 (256 MB) -> stream
// with nontemporal load/store (nt flag). Flat direct-index launch: no
// grid-stride loop, one float4 from x + one from y per thread, both loads
// issued before stores. 32768 blocks x 256 threads = max TLP.

typedef float f4 __attribute__((ext_vector_type(4)));

__global__ __launch_bounds__(256)
void copy_xy_kernel(const f4* __restrict__ x, const f4* __restrict__ y,
                    f4* __restrict__ ox, f4* __restrict__ oy,
                    size_t n4) {
    const size_t i = (size_t)blockIdx.x * 256 + threadIdx.x;
    if (i < n4) {
        f4 a = __builtin_nontemporal_load(&x[i]);
        f4 b = __builtin_nontemporal_load(&y[i]);
        __builtin_nontemporal_store(a, &ox[i]);
        __builtin_nontemporal_store(b, &oy[i]);
    }
}

extern "C" void kernel_launch(void* const* d_in, const int* in_sizes, int n_in,
                              void* d_out, int out_size, void* d_ws, size_t ws_size,
                              hipStream_t stream) {
    const size_t nx = (size_t)in_sizes[0];  // x: 128*64*64*64 f32
    const size_t ny = (size_t)in_sizes[1];  // y: same count
    const size_t n4 = nx / 4;               // 8388608 float4 per range

    const f4* x = (const f4*)d_in[0];
    const f4* y = (const f4*)d_in[1];
    f4* ox = (f4*)d_out;
    f4* oy = (f4*)((char*)d_out + nx * sizeof(float));

    const int blocks = (int)((n4 + 255) / 256);  // 32768
    copy_xy_kernel<<<blocks, 256, 0, stream>>>(x, y, ox, oy, n4);
}